// Round 8
// baseline (715.913 us; speedup 1.0000x reference)
//
#include <hip/hip_runtime.h>
#include <cstddef>
#include <cstdint>

#define B_ 16
#define H_ 16
#define NQ 8
#define D_ 128
#define E_ 2048
#define F3 6144
#define KVP 4096
#define KVT 4104
#define SCALE 0.08838834764831843f
#define NCHUNK 8
#define CHUNK 512
#define PARTSZ 1040  // 8 m + 8 l + 8*128 acc

// wave-local LDS ordering: no barrier, just drain DS ops of this wave
#define WAVE_LDS_FENCE() asm volatile("s_waitcnt lgkmcnt(0)" ::: "memory")

// ---------------- GEMM: C[M][F] = X[M][K] * W[F][K]^T (fp32) ----------------
// SPLITK>1: block z writes its partial to C + z*128*Fdim (separate buffers, no atomics).
template <int BM, int BN, int SPLITK>
__global__ __launch_bounds__(256) void gemm_xwt(const float* __restrict__ X,
                                                const float* __restrict__ W,
                                                float* __restrict__ C,
                                                int K, int Fdim) {
  constexpr int BK = 32;
  constexpr int RM = BM / 16;
  constexpr int RN = BN / 16;
  __shared__ float xs[BK][BM + 4];
  __shared__ float wss[BK][BN + 4];
  const int t = threadIdx.x;
  const int tm = t >> 4, tn = t & 15;
  const int m0 = blockIdx.y * BM, f0 = blockIdx.x * BN;
  const int kbeg = (SPLITK > 1) ? blockIdx.z * (K / SPLITK) : 0;
  const int kend = (SPLITK > 1) ? kbeg + K / SPLITK : K;
  if (SPLITK > 1) C += (size_t)blockIdx.z * 128 * Fdim;
  float acc[RM][RN];
#pragma unroll
  for (int i = 0; i < RM; ++i)
#pragma unroll
    for (int j = 0; j < RN; ++j) acc[i][j] = 0.f;

  for (int kk = kbeg; kk < kend; kk += BK) {
#pragma unroll
    for (int i = 0; i < (BM * BK) / 1024; ++i) {
      int j = t + i * 256;
      int r = j >> 3;
      int c = (j & 7) << 2;
      float4 v = *reinterpret_cast<const float4*>(&X[(size_t)(m0 + r) * K + kk + c]);
      xs[c + 0][r] = v.x; xs[c + 1][r] = v.y; xs[c + 2][r] = v.z; xs[c + 3][r] = v.w;
    }
#pragma unroll
    for (int i = 0; i < (BN * BK) / 1024; ++i) {
      int j = t + i * 256;
      int r = j >> 3;
      int c = (j & 7) << 2;
      float4 v = *reinterpret_cast<const float4*>(&W[(size_t)(f0 + r) * K + kk + c]);
      wss[c + 0][r] = v.x; wss[c + 1][r] = v.y; wss[c + 2][r] = v.z; wss[c + 3][r] = v.w;
    }
    __syncthreads();
#pragma unroll
    for (int k = 0; k < BK; ++k) {
      float xv[RM], wv[RN];
      if constexpr (RM == 4) {
        *reinterpret_cast<float4*>(xv) = *reinterpret_cast<const float4*>(&xs[k][tm * 4]);
      } else {
        *reinterpret_cast<float2*>(xv) = *reinterpret_cast<const float2*>(&xs[k][tm * 2]);
      }
      if constexpr (RN == 4) {
        *reinterpret_cast<float4*>(wv) = *reinterpret_cast<const float4*>(&wss[k][tn * 4]);
      } else {
        *reinterpret_cast<float2*>(wv) = *reinterpret_cast<const float2*>(&wss[k][tn * 2]);
      }
#pragma unroll
      for (int i = 0; i < RM; ++i)
#pragma unroll
        for (int j = 0; j < RN; ++j) acc[i][j] += xv[i] * wv[j];
    }
    __syncthreads();
  }
#pragma unroll
  for (int i = 0; i < RM; ++i) {
    float* cp = &C[(size_t)(m0 + tm * RM + i) * Fdim + f0 + tn * RN];
    if constexpr (RN == 4) {
      *reinterpret_cast<float4*>(cp) = make_float4(acc[i][0], acc[i][1], acc[i][2], acc[i][3]);
    } else {
      *reinterpret_cast<float2*>(cp) = make_float2(acc[i][0], acc[i][1]);
    }
  }
}

// o = a + b, n4 float4s, grid*block == n4
__global__ __launch_bounds__(256) void add2(const float* __restrict__ a,
                                            const float* __restrict__ b,
                                            float* __restrict__ o) {
  int i = blockIdx.x * 256 + threadIdx.x;
  float4 va = reinterpret_cast<const float4*>(a)[i];
  float4 vb = reinterpret_cast<const float4*>(b)[i];
  reinterpret_cast<float4*>(o)[i] =
      make_float4(va.x + vb.x, va.y + vb.y, va.z + vb.z, va.w + vb.w);
}

// ------- Fused KV-cache copy + flash-attention partials over past chunks -------
// grid: (NCHUNK, H, B), 256 threads = 4 waves. Each WAVE independently processes a
// private 128-row slice with its own online softmax state — zero barriers in the
// main loop. NO register prefetch (loads at use; TLP hides latency) and
// __launch_bounds__(256,4) caps VGPR<=128 -> 4 waves/SIMD, no scratch spills.
__global__ __launch_bounds__(256, 4) void attn_partial(
    const float* __restrict__ past_k, const float* __restrict__ past_v,
    const float* __restrict__ qkv_a, const float* __restrict__ qkv_b,
    float* __restrict__ out_k, float* __restrict__ out_v,
    float* __restrict__ part) {
  const int t = threadIdx.x;
  const int c = blockIdx.x, h = blockIdx.y, b = blockIdx.z;
  const int bh = b * H_ + h;
  const int l = t & 63, w = t >> 6;
  const int g = l & 31, half = l >> 5;

  __shared__ float red[4096];          // 16KB end-merge buffer [w][qi][128]
  __shared__ float scratch[4][160];    // per-wave: s(72) | p(64 @72) | f(8 @136)
  __shared__ float mw_lds[32], lw_lds[32];
  float* s_w = scratch[w];
  float* p_w = scratch[w] + 72;
  float* f_w = scratch[w] + 136;

  // Q resident in registers (sum of split-K partials): fixed f4-column g, all 8 q-rows
  float4 qreg[NQ];
#pragma unroll
  for (int qi = 0; qi < NQ; ++qi) {
    const size_t qoff = (size_t)(b * NQ + qi) * F3 + h * D_ + g * 4;
    float4 q0 = *reinterpret_cast<const float4*>(&qkv_a[qoff]);
    if (qkv_b) {
      float4 q1 = *reinterpret_cast<const float4*>(&qkv_b[qoff]);
      q0.x += q1.x; q0.y += q1.y; q0.z += q1.z; q0.w += q1.w;
    }
    qreg[qi] = q0;
  }

  const int wbase = w * 128;
  const float* gk = past_k + ((size_t)bh * KVP + (size_t)c * CHUNK) * D_;
  const float* gv = past_v + ((size_t)bh * KVP + (size_t)c * CHUNK) * D_;
  float* ok = out_k + ((size_t)bh * KVT + (size_t)c * CHUNK) * D_;
  float* ov = out_v + ((size_t)bh * KVT + (size_t)c * CHUNK) * D_;

  float4 acc[NQ];
#pragma unroll
  for (int qi = 0; qi < NQ; ++qi) acc[qi] = make_float4(0.f, 0.f, 0.f, 0.f);
  float m_run = -1e30f, l_run = 0.f;  // per-lane (sqi-group) online state

  const int b0 = g & 1, b1 = (g >> 1) & 1, b2 = (g >> 2) & 1;
  const int qsel = 4 * b0 + 2 * b1 + b2;
  const int srow = l & 7, sqi = l >> 3;

  for (int it = 0; it < 16; ++it) {
    // ---- load 4 K/V rows at use, copy-through, reg-direct scores ----
    float4 kf[4], vf[4];
#pragma unroll
    for (int j = 0; j < 4; ++j) {
      const size_t ga = (size_t)(wbase + it * 8 + half + 2 * j) * D_ + g * 4;
      kf[j] = *reinterpret_cast<const float4*>(&gk[ga]);
      vf[j] = *reinterpret_cast<const float4*>(&gv[ga]);
    }
#pragma unroll
    for (int j = 0; j < 4; ++j) {
      const int r = half + 2 * j;
      const size_t ga = (size_t)(wbase + it * 8 + r) * D_ + g * 4;
      *reinterpret_cast<float4*>(&ok[ga]) = kf[j];
      *reinterpret_cast<float4*>(&ov[ga]) = vf[j];
      float sp[NQ];
#pragma unroll
      for (int qi = 0; qi < NQ; ++qi)
        sp[qi] = kf[j].x * qreg[qi].x + kf[j].y * qreg[qi].y +
                 kf[j].z * qreg[qi].z + kf[j].w * qreg[qi].w;
      // butterfly: 8 vals -> 1 per lane over this 32-lane half (row r)
      float v1[4];
#pragma unroll
      for (int jj = 0; jj < 4; ++jj) {
        float x = b0 ? sp[jj] : sp[jj + 4];
        v1[jj] = (b0 ? sp[jj + 4] : sp[jj]) + __shfl_xor(x, 1);
      }
      float v2[2];
#pragma unroll
      for (int jj = 0; jj < 2; ++jj) {
        float x = b1 ? v1[jj] : v1[jj + 2];
        v2[jj] = (b1 ? v1[jj + 2] : v1[jj]) + __shfl_xor(x, 2);
      }
      float v3;
      {
        float x = b2 ? v2[0] : v2[1];
        v3 = (b2 ? v2[1] : v2[0]) + __shfl_xor(x, 4);
      }
      v3 += __shfl_xor(v3, 8);
      v3 += __shfl_xor(v3, 16);
      if (g < 8) s_w[r * 9 + qsel] = v3;
    }
    WAVE_LDS_FENCE();  // s_w visible wave-wide

    // ---- wave-local online softmax (lane role: row=srow, qi=sqi) ----
    {
      float s = s_w[srow * 9 + sqi] * SCALE;
      float cmax = s;
      cmax = fmaxf(cmax, __shfl_xor(cmax, 1));
      cmax = fmaxf(cmax, __shfl_xor(cmax, 2));
      cmax = fmaxf(cmax, __shfl_xor(cmax, 4));
      float mn = fmaxf(m_run, cmax);
      float p = __expf(s - mn);
      float ps = p;
      ps += __shfl_xor(ps, 1);
      ps += __shfl_xor(ps, 2);
      ps += __shfl_xor(ps, 4);
      float f = __expf(m_run - mn);
      p_w[srow * 8 + sqi] = p;
      if (srow == 0) f_w[sqi] = f;
      l_run = l_run * f + ps;
      m_run = mn;
    }
    WAVE_LDS_FENCE();  // p_w/f_w visible wave-wide

    // ---- PV on register V rows ----
    {
      float4 f0 = *reinterpret_cast<const float4*>(&f_w[0]);
      float4 f1 = *reinterpret_cast<const float4*>(&f_w[4]);
      acc[0].x *= f0.x; acc[0].y *= f0.x; acc[0].z *= f0.x; acc[0].w *= f0.x;
      acc[1].x *= f0.y; acc[1].y *= f0.y; acc[1].z *= f0.y; acc[1].w *= f0.y;
      acc[2].x *= f0.z; acc[2].y *= f0.z; acc[2].z *= f0.z; acc[2].w *= f0.z;
      acc[3].x *= f0.w; acc[3].y *= f0.w; acc[3].z *= f0.w; acc[3].w *= f0.w;
      acc[4].x *= f1.x; acc[4].y *= f1.x; acc[4].z *= f1.x; acc[4].w *= f1.x;
      acc[5].x *= f1.y; acc[5].y *= f1.y; acc[5].z *= f1.y; acc[5].w *= f1.y;
      acc[6].x *= f1.z; acc[6].y *= f1.z; acc[6].z *= f1.z; acc[6].w *= f1.z;
      acc[7].x *= f1.w; acc[7].y *= f1.w; acc[7].z *= f1.w; acc[7].w *= f1.w;
#pragma unroll
      for (int j = 0; j < 4; ++j) {
        const int r = half + 2 * j;
        float4 pa = *reinterpret_cast<const float4*>(&p_w[r * 8]);      // broadcast
        float4 pc = *reinterpret_cast<const float4*>(&p_w[r * 8 + 4]);  // broadcast
        acc[0].x += pa.x * vf[j].x; acc[0].y += pa.x * vf[j].y; acc[0].z += pa.x * vf[j].z; acc[0].w += pa.x * vf[j].w;
        acc[1].x += pa.y * vf[j].x; acc[1].y += pa.y * vf[j].y; acc[1].z += pa.y * vf[j].z; acc[1].w += pa.y * vf[j].w;
        acc[2].x += pa.z * vf[j].x; acc[2].y += pa.z * vf[j].y; acc[2].z += pa.z * vf[j].z; acc[2].w += pa.z * vf[j].w;
        acc[3].x += pa.w * vf[j].x; acc[3].y += pa.w * vf[j].y; acc[3].z += pa.w * vf[j].z; acc[3].w += pa.w * vf[j].w;
        acc[4].x += pc.x * vf[j].x; acc[4].y += pc.x * vf[j].y; acc[4].z += pc.x * vf[j].z; acc[4].w += pc.x * vf[j].w;
        acc[5].x += pc.y * vf[j].x; acc[5].y += pc.y * vf[j].y; acc[5].z += pc.y * vf[j].z; acc[5].w += pc.y * vf[j].w;
        acc[6].x += pc.z * vf[j].x; acc[6].y += pc.z * vf[j].y; acc[6].z += pc.z * vf[j].z; acc[6].w += pc.z * vf[j].w;
        acc[7].x += pc.w * vf[j].x; acc[7].y += pc.w * vf[j].y; acc[7].z += pc.w * vf[j].z; acc[7].w += pc.w * vf[j].w;
      }
    }
  }

  // ---- combine the two halves' row-parity partials (same column g) ----
#pragma unroll
  for (int qi = 0; qi < NQ; ++qi) {
    acc[qi].x += __shfl_xor(acc[qi].x, 32);
    acc[qi].y += __shfl_xor(acc[qi].y, 32);
    acc[qi].z += __shfl_xor(acc[qi].z, 32);
    acc[qi].w += __shfl_xor(acc[qi].w, 32);
  }

  // ---- publish wave partials, single block barrier, merge 4 waves ----
  if (srow == 0) { mw_lds[w * 8 + sqi] = m_run; lw_lds[w * 8 + sqi] = l_run; }
  if (half == 0) {
#pragma unroll
    for (int qi = 0; qi < NQ; ++qi)
      *reinterpret_cast<float4*>(&red[w * 1024 + qi * 128 + g * 4]) = acc[qi];
  }
  __syncthreads();

  {
    const int col4 = t & 31, qi = (t >> 5) & 7;
    float M = mw_lds[qi];
    M = fmaxf(M, mw_lds[8 + qi]);
    M = fmaxf(M, mw_lds[16 + qi]);
    M = fmaxf(M, mw_lds[24 + qi]);
    float den = 0.f;
    float4 num = make_float4(0.f, 0.f, 0.f, 0.f);
#pragma unroll
    for (int ww = 0; ww < 4; ++ww) {
      float wt = __expf(mw_lds[ww * 8 + qi] - M);
      den += wt * lw_lds[ww * 8 + qi];
      float4 a = *reinterpret_cast<const float4*>(&red[ww * 1024 + qi * 128 + col4 * 4]);
      num.x += wt * a.x; num.y += wt * a.y; num.z += wt * a.z; num.w += wt * a.w;
    }
    float* pb = part + ((size_t)bh * NCHUNK + c) * PARTSZ;
    *reinterpret_cast<float4*>(&pb[16 + qi * 128 + col4 * 4]) = num;
    if (col4 == 0) { pb[qi] = M; pb[8 + qi] = den; }
  }
}

// ------- new-token chunk + combine partials -> attention output (pre-proj) -------
// grid: (H, B), 256 threads.
__global__ __launch_bounds__(256) void attn_combine(
    const float* __restrict__ qkv_a, const float* __restrict__ qkv_b,
    const float* __restrict__ part, float* __restrict__ out_k,
    float* __restrict__ out_v, float* __restrict__ attn) {
  const int t = threadIdx.x;
  const int h = blockIdx.x, b = blockIdx.y;
  const int bh = b * H_ + h;
  __shared__ float q_lds[NQ * 132];
  __shared__ float kn_lds[NQ * 132];
  __shared__ float vn_lds[NQ * 132];
  __shared__ float p9[NQ * 12];
  __shared__ float m9_lds[NQ], s9_lds[NQ];
  {
    int n = t >> 5, g = t & 31;
    const size_t soff = (size_t)(b * NQ + n) * F3 + h * D_ + g * 4;
    float4 qv = *reinterpret_cast<const float4*>(&qkv_a[soff]);
    float4 kv = *reinterpret_cast<const float4*>(&qkv_a[soff + E_]);
    float4 vv = *reinterpret_cast<const float4*>(&qkv_a[soff + 2 * E_]);
    if (qkv_b) {
      float4 q1 = *reinterpret_cast<const float4*>(&qkv_b[soff]);
      float4 k1 = *reinterpret_cast<const float4*>(&qkv_b[soff + E_]);
      float4 v1 = *reinterpret_cast<const float4*>(&qkv_b[soff + 2 * E_]);
      qv.x += q1.x; qv.y += q1.y; qv.z += q1.z; qv.w += q1.w;
      kv.x += k1.x; kv.y += k1.y; kv.z += k1.z; kv.w += k1.w;
      vv.x += v1.x; vv.y += v1.y; vv.z += v1.z; vv.w += v1.w;
    }
    *reinterpret_cast<float4*>(&q_lds[n * 132 + g * 4]) = qv;
    *reinterpret_cast<float4*>(&kn_lds[n * 132 + g * 4]) = kv;
    *reinterpret_cast<float4*>(&vn_lds[n * 132 + g * 4]) = vv;
    *reinterpret_cast<float4*>(&out_k[((size_t)bh * KVT + KVP + n) * D_ + g * 4]) = kv;
    *reinterpret_cast<float4*>(&out_v[((size_t)bh * KVT + KVP + n) * D_ + g * 4]) = vv;
  }
  __syncthreads();
  if (t < 64) {
    int nq = t >> 3, nk = t & 7;
    float s = 0.f;
#pragma unroll
    for (int g = 0; g < 32; ++g) {
      float4 qv = *reinterpret_cast<const float4*>(&q_lds[nq * 132 + g * 4]);
      float4 kv = *reinterpret_cast<const float4*>(&kn_lds[nk * 132 + g * 4]);
      s += qv.x * kv.x + qv.y * kv.y + qv.z * kv.z + qv.w * kv.w;
    }
    s *= SCALE;
    float mx = s;
#pragma unroll
    for (int o = 4; o > 0; o >>= 1) mx = fmaxf(mx, __shfl_xor(mx, o));
    float p = __expf(s - mx);
    float sm = p;
#pragma unroll
    for (int o = 4; o > 0; o >>= 1) sm += __shfl_xor(sm, o);
    p9[nk * 12 + nq] = p;
    if (nk == 0) { m9_lds[nq] = mx; s9_lds[nq] = sm; }
  }
  __syncthreads();
  const int qg = t >> 7, dcol = t & 127;
  const float* pb = part + (size_t)bh * NCHUNK * PARTSZ;
#pragma unroll
  for (int jq = 0; jq < 4; ++jq) {
    int qi = qg * 4 + jq;
    float M = m9_lds[qi];
#pragma unroll
    for (int c = 0; c < NCHUNK; ++c) M = fmaxf(M, pb[(size_t)c * PARTSZ + qi]);
    float num = 0.f, den = 0.f;
#pragma unroll
    for (int c = 0; c < NCHUNK; ++c) {
      const float* pc = pb + (size_t)c * PARTSZ;
      float wgt = __expf(pc[qi] - M);
      den += wgt * pc[8 + qi];
      num += wgt * pc[16 + (size_t)qi * D_ + dcol];
    }
    float acc9 = 0.f;
#pragma unroll
    for (int r = 0; r < NQ; ++r) acc9 += p9[r * 12 + qi] * vn_lds[r * 132 + dcol];
    float w9 = __expf(m9_lds[qi] - M);
    num += w9 * acc9;
    den += w9 * s9_lds[qi];
    attn[((size_t)(b * NQ + qi)) * E_ + h * D_ + dcol] = num / den;
  }
}

extern "C" void kernel_launch(void* const* d_in, const int* in_sizes, int n_in,
                              void* d_out, int out_size, void* d_ws, size_t ws_size,
                              hipStream_t stream) {
  const float* x      = (const float*)d_in[0];
  const float* past_k = (const float*)d_in[1];
  const float* past_v = (const float*)d_in[2];
  const float* W_qkv  = (const float*)d_in[3];
  const float* W_out  = (const float*)d_in[4];

  float* out   = (float*)d_out;
  float* out_k = out + (size_t)B_ * NQ * E_;
  float* out_v = out_k + (size_t)B_ * H_ * KVT * D_;

  const size_t QKV_N  = (size_t)B_ * NQ * F3;               // 786432
  const size_t PART_N = (size_t)B_ * H_ * NCHUNK * PARTSZ;  // 2129920
  const size_t ATTN_N = (size_t)B_ * NQ * E_;               // 262144
  const size_t need2  = (2 * QKV_N + PART_N + 3 * ATTN_N) * sizeof(float);

  float* ws = (float*)d_ws;
  const bool split2 = ws_size >= need2;

  float* pq0  = ws;
  float* pq1  = split2 ? ws + QKV_N : nullptr;
  float* part = ws + (split2 ? 2 : 1) * QKV_N;
  float* attn = part + PART_N;
  float* po0  = attn + ATTN_N;

  if (split2) {
    gemm_xwt<64, 64, 2><<<dim3(F3 / 64, 2, 2), 256, 0, stream>>>(x, W_qkv, pq0, E_, F3);
  } else {
    gemm_xwt<64, 64, 1><<<dim3(F3 / 64, 2), 256, 0, stream>>>(x, W_qkv, pq0, E_, F3);
  }
  attn_partial<<<dim3(NCHUNK, H_, B_), 256, 0, stream>>>(past_k, past_v, pq0, pq1,
                                                         out_k, out_v, part);
  attn_combine<<<dim3(H_, B_), 256, 0, stream>>>(pq0, pq1, part, out_k, out_v, attn);
  if (split2) {
    gemm_xwt<64, 64, 2><<<dim3(E_ / 64, 2, 2), 256, 0, stream>>>(attn, W_out, po0, E_, E_);
    add2<<<dim3(ATTN_N / 1024), 256, 0, stream>>>(po0, po0 + ATTN_N, out);
  } else {
    gemm_xwt<64, 64, 1><<<dim3(E_ / 64, 2), 256, 0, stream>>>(attn, W_out, out, E_, E_);
  }
}

// Round 9
// 582.246 us; speedup vs baseline: 1.2296x; 1.2296x over previous
//
#include <hip/hip_runtime.h>
#include <cstddef>
#include <cstdint>

#define B_ 16
#define H_ 16
#define NQ 8
#define D_ 128
#define E_ 2048
#define F3 6144
#define KVP 4096
#define KVT 4104
#define SCALE 0.08838834764831843f
#define NCHUNK 8
#define CHUNK 512
#define PARTSZ 1040  // 8 m + 8 l + 8*128 acc

// wave-local LDS ordering: no barrier, just drain DS ops of this wave
#define WAVE_LDS_FENCE() asm volatile("s_waitcnt lgkmcnt(0)" ::: "memory")

// ---------------- GEMM: C[M][F] = X[M][K] * W[F][K]^T (fp32) ----------------
// SPLITK>1: block z writes its partial to C + z*128*Fdim (separate buffers, no atomics).
template <int BM, int BN, int SPLITK>
__global__ __launch_bounds__(256) void gemm_xwt(const float* __restrict__ X,
                                                const float* __restrict__ W,
                                                float* __restrict__ C,
                                                int K, int Fdim) {
  constexpr int BK = 32;
  constexpr int RM = BM / 16;
  constexpr int RN = BN / 16;
  __shared__ float xs[BK][BM + 4];
  __shared__ float wss[BK][BN + 4];
  const int t = threadIdx.x;
  const int tm = t >> 4, tn = t & 15;
  const int m0 = blockIdx.y * BM, f0 = blockIdx.x * BN;
  const int kbeg = (SPLITK > 1) ? blockIdx.z * (K / SPLITK) : 0;
  const int kend = (SPLITK > 1) ? kbeg + K / SPLITK : K;
  if (SPLITK > 1) C += (size_t)blockIdx.z * 128 * Fdim;
  float acc[RM][RN];
#pragma unroll
  for (int i = 0; i < RM; ++i)
#pragma unroll
    for (int j = 0; j < RN; ++j) acc[i][j] = 0.f;

  for (int kk = kbeg; kk < kend; kk += BK) {
#pragma unroll
    for (int i = 0; i < (BM * BK) / 1024; ++i) {
      int j = t + i * 256;
      int r = j >> 3;
      int c = (j & 7) << 2;
      float4 v = *reinterpret_cast<const float4*>(&X[(size_t)(m0 + r) * K + kk + c]);
      xs[c + 0][r] = v.x; xs[c + 1][r] = v.y; xs[c + 2][r] = v.z; xs[c + 3][r] = v.w;
    }
#pragma unroll
    for (int i = 0; i < (BN * BK) / 1024; ++i) {
      int j = t + i * 256;
      int r = j >> 3;
      int c = (j & 7) << 2;
      float4 v = *reinterpret_cast<const float4*>(&W[(size_t)(f0 + r) * K + kk + c]);
      wss[c + 0][r] = v.x; wss[c + 1][r] = v.y; wss[c + 2][r] = v.z; wss[c + 3][r] = v.w;
    }
    __syncthreads();
#pragma unroll
    for (int k = 0; k < BK; ++k) {
      float xv[RM], wv[RN];
      if constexpr (RM == 4) {
        *reinterpret_cast<float4*>(xv) = *reinterpret_cast<const float4*>(&xs[k][tm * 4]);
      } else {
        *reinterpret_cast<float2*>(xv) = *reinterpret_cast<const float2*>(&xs[k][tm * 2]);
      }
      if constexpr (RN == 4) {
        *reinterpret_cast<float4*>(wv) = *reinterpret_cast<const float4*>(&wss[k][tn * 4]);
      } else {
        *reinterpret_cast<float2*>(wv) = *reinterpret_cast<const float2*>(&wss[k][tn * 2]);
      }
#pragma unroll
      for (int i = 0; i < RM; ++i)
#pragma unroll
        for (int j = 0; j < RN; ++j) acc[i][j] += xv[i] * wv[j];
    }
    __syncthreads();
  }
#pragma unroll
  for (int i = 0; i < RM; ++i) {
    float* cp = &C[(size_t)(m0 + tm * RM + i) * Fdim + f0 + tn * RN];
    if constexpr (RN == 4) {
      *reinterpret_cast<float4*>(cp) = make_float4(acc[i][0], acc[i][1], acc[i][2], acc[i][3]);
    } else {
      *reinterpret_cast<float2*>(cp) = make_float2(acc[i][0], acc[i][1]);
    }
  }
}

// o = a + b, n4 float4s, grid*block == n4
__global__ __launch_bounds__(256) void add2(const float* __restrict__ a,
                                            const float* __restrict__ b,
                                            float* __restrict__ o) {
  int i = blockIdx.x * 256 + threadIdx.x;
  float4 va = reinterpret_cast<const float4*>(a)[i];
  float4 vb = reinterpret_cast<const float4*>(b)[i];
  reinterpret_cast<float4*>(o)[i] =
      make_float4(va.x + vb.x, va.y + vb.y, va.z + vb.z, va.w + vb.w);
}

// ------- Fused KV-cache copy + flash-attention partials over past chunks -------
// grid: (NCHUNK, H, B), 256 threads = 4 waves; wave w owns rows [128w,128w+128).
// In-register online softmax: after the score butterfly every lane holds full dots
// for its 4 rows (qi=qsel); max/exp/sum complete via registers + shfl_xor(32).
// Only P (1 ds_write_b32/lane) and f (8 lanes) touch LDS; ONE fence per iter.
__global__ __launch_bounds__(256) void attn_partial(
    const float* __restrict__ past_k, const float* __restrict__ past_v,
    const float* __restrict__ qkv_a, const float* __restrict__ qkv_b,
    float* __restrict__ out_k, float* __restrict__ out_v,
    float* __restrict__ part) {
  const int t = threadIdx.x;
  const int c = blockIdx.x, h = blockIdx.y, b = blockIdx.z;
  const int bh = b * H_ + h;
  const int l = t & 63, w = t >> 6;
  const int g = l & 31, half = l >> 5;

  __shared__ float red[4096];        // 16KB end-merge buffer [w][qi][128]
  __shared__ float pw_s[4][72];      // per-wave: p[8 rows][8 qi] | f[8] @64
  __shared__ float mw_lds[32], lw_lds[32];
  float* p_w = pw_s[w];
  float* f_w = pw_s[w] + 64;

  // Q resident in registers, pre-scaled by SCALE (fixed f4-column g, all 8 q-rows)
  float4 qreg[NQ];
#pragma unroll
  for (int qi = 0; qi < NQ; ++qi) {
    const size_t qoff = (size_t)(b * NQ + qi) * F3 + h * D_ + g * 4;
    float4 q0 = *reinterpret_cast<const float4*>(&qkv_a[qoff]);
    if (qkv_b) {
      float4 q1 = *reinterpret_cast<const float4*>(&qkv_b[qoff]);
      q0.x += q1.x; q0.y += q1.y; q0.z += q1.z; q0.w += q1.w;
    }
    q0.x *= SCALE; q0.y *= SCALE; q0.z *= SCALE; q0.w *= SCALE;
    qreg[qi] = q0;
  }

  const int wbase = w * 128;
  const float* gk = past_k + ((size_t)bh * KVP + (size_t)c * CHUNK) * D_;
  const float* gv = past_v + ((size_t)bh * KVP + (size_t)c * CHUNK) * D_;
  float* ok = out_k + ((size_t)bh * KVT + (size_t)c * CHUNK) * D_;
  float* ov = out_v + ((size_t)bh * KVT + (size_t)c * CHUNK) * D_;

  float4 acc[NQ];
#pragma unroll
  for (int qi = 0; qi < NQ; ++qi) acc[qi] = make_float4(0.f, 0.f, 0.f, 0.f);
  float m_run = -1e30f, l_run = 0.f;  // per-lane state for qi = qsel

  const int b0 = g & 1, b1 = (g >> 1) & 1, b2 = (g >> 2) & 1;
  const int qsel = 4 * b0 + 2 * b1 + b2;  // qi this lane's butterfly output maps to
  const int cp = g >> 3;                  // butterfly copy index 0..3 -> row half+2*cp

  for (int it = 0; it < 16; ++it) {
    // ---- load 4 K/V rows (parity-interleaved), copy-through, reg-direct scores ----
    float4 kf[4], vf[4];
#pragma unroll
    for (int j = 0; j < 4; ++j) {
      const size_t ga = (size_t)(wbase + it * 8 + half + 2 * j) * D_ + g * 4;
      kf[j] = *reinterpret_cast<const float4*>(&gk[ga]);
      vf[j] = *reinterpret_cast<const float4*>(&gv[ga]);
    }
    float s4[4];
#pragma unroll
    for (int j = 0; j < 4; ++j) {
      const size_t ga = (size_t)(wbase + it * 8 + half + 2 * j) * D_ + g * 4;
      *reinterpret_cast<float4*>(&ok[ga]) = kf[j];
      *reinterpret_cast<float4*>(&ov[ga]) = vf[j];
      float sp[NQ];
#pragma unroll
      for (int qi = 0; qi < NQ; ++qi)
        sp[qi] = kf[j].x * qreg[qi].x + kf[j].y * qreg[qi].y +
                 kf[j].z * qreg[qi].z + kf[j].w * qreg[qi].w;
      // butterfly: 8 vals -> full dot on every lane of the 32-lane half (qi=qsel)
      float v1[4];
#pragma unroll
      for (int jj = 0; jj < 4; ++jj) {
        float x = b0 ? sp[jj] : sp[jj + 4];
        v1[jj] = (b0 ? sp[jj + 4] : sp[jj]) + __shfl_xor(x, 1);
      }
      float v2[2];
#pragma unroll
      for (int jj = 0; jj < 2; ++jj) {
        float x = b1 ? v1[jj] : v1[jj + 2];
        v2[jj] = (b1 ? v1[jj + 2] : v1[jj]) + __shfl_xor(x, 2);
      }
      float v3;
      {
        float x = b2 ? v2[0] : v2[1];
        v3 = (b2 ? v2[1] : v2[0]) + __shfl_xor(x, 4);
      }
      v3 += __shfl_xor(v3, 8);
      v3 += __shfl_xor(v3, 16);
      s4[j] = v3;
    }

    // ---- in-register online softmax for qi = qsel over this iter's 8 rows ----
    {
      float mt = fmaxf(fmaxf(s4[0], s4[1]), fmaxf(s4[2], s4[3]));
      mt = fmaxf(mt, __shfl_xor(mt, 32));   // other parity's rows
      float mn = fmaxf(m_run, mt);
      float f = __expf(m_run - mn);
      s4[0] = __expf(s4[0] - mn);
      s4[1] = __expf(s4[1] - mn);
      s4[2] = __expf(s4[2] - mn);
      s4[3] = __expf(s4[3] - mn);
      float ps = (s4[0] + s4[1]) + (s4[2] + s4[3]);
      ps += __shfl_xor(ps, 32);
      l_run = l_run * f + ps;
      m_run = mn;
      // publish: each butterfly copy writes one row's p (64 lanes -> 64 slots)
      p_w[(half + 2 * cp) * 8 + qsel] = s4[cp];
      if (l < 8) f_w[qsel] = f;
    }
    WAVE_LDS_FENCE();  // p/f visible wave-wide

    // ---- PV on register V rows (own parity; twin lane covers the other) ----
    {
      float4 f0 = *reinterpret_cast<const float4*>(&f_w[0]);
      float4 f1 = *reinterpret_cast<const float4*>(&f_w[4]);
      acc[0].x *= f0.x; acc[0].y *= f0.x; acc[0].z *= f0.x; acc[0].w *= f0.x;
      acc[1].x *= f0.y; acc[1].y *= f0.y; acc[1].z *= f0.y; acc[1].w *= f0.y;
      acc[2].x *= f0.z; acc[2].y *= f0.z; acc[2].z *= f0.z; acc[2].w *= f0.z;
      acc[3].x *= f0.w; acc[3].y *= f0.w; acc[3].z *= f0.w; acc[3].w *= f0.w;
      acc[4].x *= f1.x; acc[4].y *= f1.x; acc[4].z *= f1.x; acc[4].w *= f1.x;
      acc[5].x *= f1.y; acc[5].y *= f1.y; acc[5].z *= f1.y; acc[5].w *= f1.y;
      acc[6].x *= f1.z; acc[6].y *= f1.z; acc[6].z *= f1.z; acc[6].w *= f1.z;
      acc[7].x *= f1.w; acc[7].y *= f1.w; acc[7].z *= f1.w; acc[7].w *= f1.w;
#pragma unroll
      for (int j = 0; j < 4; ++j) {
        const int r = half + 2 * j;
        float4 pa = *reinterpret_cast<const float4*>(&p_w[r * 8]);      // broadcast
        float4 pc4 = *reinterpret_cast<const float4*>(&p_w[r * 8 + 4]); // broadcast
        acc[0].x += pa.x * vf[j].x; acc[0].y += pa.x * vf[j].y; acc[0].z += pa.x * vf[j].z; acc[0].w += pa.x * vf[j].w;
        acc[1].x += pa.y * vf[j].x; acc[1].y += pa.y * vf[j].y; acc[1].z += pa.y * vf[j].z; acc[1].w += pa.y * vf[j].w;
        acc[2].x += pa.z * vf[j].x; acc[2].y += pa.z * vf[j].y; acc[2].z += pa.z * vf[j].z; acc[2].w += pa.z * vf[j].w;
        acc[3].x += pa.w * vf[j].x; acc[3].y += pa.w * vf[j].y; acc[3].z += pa.w * vf[j].z; acc[3].w += pa.w * vf[j].w;
        acc[4].x += pc4.x * vf[j].x; acc[4].y += pc4.x * vf[j].y; acc[4].z += pc4.x * vf[j].z; acc[4].w += pc4.x * vf[j].w;
        acc[5].x += pc4.y * vf[j].x; acc[5].y += pc4.y * vf[j].y; acc[5].z += pc4.y * vf[j].z; acc[5].w += pc4.y * vf[j].w;
        acc[6].x += pc4.z * vf[j].x; acc[6].y += pc4.z * vf[j].y; acc[6].z += pc4.z * vf[j].z; acc[6].w += pc4.z * vf[j].w;
        acc[7].x += pc4.w * vf[j].x; acc[7].y += pc4.w * vf[j].y; acc[7].z += pc4.w * vf[j].z; acc[7].w += pc4.w * vf[j].w;
      }
    }
    // next iter's p_w writes are same-wave, later in program order -> safe
  }

  // ---- merge the two parity halves (same column g) ----
#pragma unroll
  for (int qi = 0; qi < NQ; ++qi) {
    acc[qi].x += __shfl_xor(acc[qi].x, 32);
    acc[qi].y += __shfl_xor(acc[qi].y, 32);
    acc[qi].z += __shfl_xor(acc[qi].z, 32);
    acc[qi].w += __shfl_xor(acc[qi].w, 32);
  }

  // ---- publish wave partials, single block barrier, merge 4 waves ----
  if (l < 8) { mw_lds[w * 8 + qsel] = m_run; lw_lds[w * 8 + qsel] = l_run; }
  if (half == 0) {
#pragma unroll
    for (int qi = 0; qi < NQ; ++qi)
      *reinterpret_cast<float4*>(&red[w * 1024 + qi * 128 + g * 4]) = acc[qi];
  }
  __syncthreads();

  {
    const int col4 = t & 31, qi = (t >> 5) & 7;
    float M = mw_lds[qi];
    M = fmaxf(M, mw_lds[8 + qi]);
    M = fmaxf(M, mw_lds[16 + qi]);
    M = fmaxf(M, mw_lds[24 + qi]);
    float den = 0.f;
    float4 num = make_float4(0.f, 0.f, 0.f, 0.f);
#pragma unroll
    for (int ww = 0; ww < 4; ++ww) {
      float wt = __expf(mw_lds[ww * 8 + qi] - M);
      den += wt * lw_lds[ww * 8 + qi];
      float4 a = *reinterpret_cast<const float4*>(&red[ww * 1024 + qi * 128 + col4 * 4]);
      num.x += wt * a.x; num.y += wt * a.y; num.z += wt * a.z; num.w += wt * a.w;
    }
    float* pb = part + ((size_t)bh * NCHUNK + c) * PARTSZ;
    *reinterpret_cast<float4*>(&pb[16 + qi * 128 + col4 * 4]) = num;
    if (col4 == 0) { pb[qi] = M; pb[8 + qi] = den; }
  }
}

// ------- new-token chunk + combine partials -> attention output (pre-proj) -------
// grid: (H, B), 256 threads.
__global__ __launch_bounds__(256) void attn_combine(
    const float* __restrict__ qkv_a, const float* __restrict__ qkv_b,
    const float* __restrict__ part, float* __restrict__ out_k,
    float* __restrict__ out_v, float* __restrict__ attn) {
  const int t = threadIdx.x;
  const int h = blockIdx.x, b = blockIdx.y;
  const int bh = b * H_ + h;
  __shared__ float q_lds[NQ * 132];
  __shared__ float kn_lds[NQ * 132];
  __shared__ float vn_lds[NQ * 132];
  __shared__ float p9[NQ * 12];
  __shared__ float m9_lds[NQ], s9_lds[NQ];
  {
    int n = t >> 5, g = t & 31;
    const size_t soff = (size_t)(b * NQ + n) * F3 + h * D_ + g * 4;
    float4 qv = *reinterpret_cast<const float4*>(&qkv_a[soff]);
    float4 kv = *reinterpret_cast<const float4*>(&qkv_a[soff + E_]);
    float4 vv = *reinterpret_cast<const float4*>(&qkv_a[soff + 2 * E_]);
    if (qkv_b) {
      float4 q1 = *reinterpret_cast<const float4*>(&qkv_b[soff]);
      float4 k1 = *reinterpret_cast<const float4*>(&qkv_b[soff + E_]);
      float4 v1 = *reinterpret_cast<const float4*>(&qkv_b[soff + 2 * E_]);
      qv.x += q1.x; qv.y += q1.y; qv.z += q1.z; qv.w += q1.w;
      kv.x += k1.x; kv.y += k1.y; kv.z += k1.z; kv.w += k1.w;
      vv.x += v1.x; vv.y += v1.y; vv.z += v1.z; vv.w += v1.w;
    }
    *reinterpret_cast<float4*>(&q_lds[n * 132 + g * 4]) = qv;
    *reinterpret_cast<float4*>(&kn_lds[n * 132 + g * 4]) = kv;
    *reinterpret_cast<float4*>(&vn_lds[n * 132 + g * 4]) = vv;
    *reinterpret_cast<float4*>(&out_k[((size_t)bh * KVT + KVP + n) * D_ + g * 4]) = kv;
    *reinterpret_cast<float4*>(&out_v[((size_t)bh * KVT + KVP + n) * D_ + g * 4]) = vv;
  }
  __syncthreads();
  if (t < 64) {
    int nq = t >> 3, nk = t & 7;
    float s = 0.f;
#pragma unroll
    for (int g = 0; g < 32; ++g) {
      float4 qv = *reinterpret_cast<const float4*>(&q_lds[nq * 132 + g * 4]);
      float4 kv = *reinterpret_cast<const float4*>(&kn_lds[nk * 132 + g * 4]);
      s += qv.x * kv.x + qv.y * kv.y + qv.z * kv.z + qv.w * kv.w;
    }
    s *= SCALE;
    float mx = s;
#pragma unroll
    for (int o = 4; o > 0; o >>= 1) mx = fmaxf(mx, __shfl_xor(mx, o));
    float p = __expf(s - mx);
    float sm = p;
#pragma unroll
    for (int o = 4; o > 0; o >>= 1) sm += __shfl_xor(sm, o);
    p9[nk * 12 + nq] = p;
    if (nk == 0) { m9_lds[nq] = mx; s9_lds[nq] = sm; }
  }
  __syncthreads();
  const int qg = t >> 7, dcol = t & 127;
  const float* pb = part + (size_t)bh * NCHUNK * PARTSZ;
#pragma unroll
  for (int jq = 0; jq < 4; ++jq) {
    int qi = qg * 4 + jq;
    float M = m9_lds[qi];
#pragma unroll
    for (int c = 0; c < NCHUNK; ++c) M = fmaxf(M, pb[(size_t)c * PARTSZ + qi]);
    float num = 0.f, den = 0.f;
#pragma unroll
    for (int c = 0; c < NCHUNK; ++c) {
      const float* pc = pb + (size_t)c * PARTSZ;
      float wgt = __expf(pc[qi] - M);
      den += wgt * pc[8 + qi];
      num += wgt * pc[16 + (size_t)qi * D_ + dcol];
    }
    float acc9 = 0.f;
#pragma unroll
    for (int r = 0; r < NQ; ++r) acc9 += p9[r * 12 + qi] * vn_lds[r * 132 + dcol];
    float w9 = __expf(m9_lds[qi] - M);
    num += w9 * acc9;
    den += w9 * s9_lds[qi];
    attn[((size_t)(b * NQ + qi)) * E_ + h * D_ + dcol] = num / den;
  }
}

extern "C" void kernel_launch(void* const* d_in, const int* in_sizes, int n_in,
                              void* d_out, int out_size, void* d_ws, size_t ws_size,
                              hipStream_t stream) {
  const float* x      = (const float*)d_in[0];
  const float* past_k = (const float*)d_in[1];
  const float* past_v = (const float*)d_in[2];
  const float* W_qkv  = (const float*)d_in[3];
  const float* W_out  = (const float*)d_in[4];

  float* out   = (float*)d_out;
  float* out_k = out + (size_t)B_ * NQ * E_;
  float* out_v = out_k + (size_t)B_ * H_ * KVT * D_;

  const size_t QKV_N  = (size_t)B_ * NQ * F3;               // 786432
  const size_t PART_N = (size_t)B_ * H_ * NCHUNK * PARTSZ;  // 2129920
  const size_t ATTN_N = (size_t)B_ * NQ * E_;               // 262144
  const size_t need2  = (2 * QKV_N + PART_N + 3 * ATTN_N) * sizeof(float);

  float* ws = (float*)d_ws;
  const bool split2 = ws_size >= need2;

  float* pq0  = ws;
  float* pq1  = split2 ? ws + QKV_N : nullptr;
  float* part = ws + (split2 ? 2 : 1) * QKV_N;
  float* attn = part + PART_N;
  float* po0  = attn + ATTN_N;

  if (split2) {
    gemm_xwt<64, 64, 2><<<dim3(F3 / 64, 2, 2), 256, 0, stream>>>(x, W_qkv, pq0, E_, F3);
  } else {
    gemm_xwt<64, 64, 1><<<dim3(F3 / 64, 2), 256, 0, stream>>>(x, W_qkv, pq0, E_, F3);
  }
  attn_partial<<<dim3(NCHUNK, H_, B_), 256, 0, stream>>>(past_k, past_v, pq0, pq1,
                                                         out_k, out_v, part);
  attn_combine<<<dim3(H_, B_), 256, 0, stream>>>(pq0, pq1, part, out_k, out_v, attn);
  if (split2) {
    gemm_xwt<64, 64, 2><<<dim3(E_ / 64, 2, 2), 256, 0, stream>>>(attn, W_out, po0, E_, E_);
    add2<<<dim3(ATTN_N / 1024), 256, 0, stream>>>(po0, po0 + ATTN_N, out);
  } else {
    gemm_xwt<64, 64, 1><<<dim3(E_ / 64, 2), 256, 0, stream>>>(attn, W_out, out, E_, E_);
  }
}

// Round 10
// 532.573 us; speedup vs baseline: 1.3443x; 1.0933x over previous
//
#include <hip/hip_runtime.h>
#include <cstddef>
#include <cstdint>

#define B_ 16
#define H_ 16
#define NQ 8
#define D_ 128
#define E_ 2048
#define F3 6144
#define KVP 4096
#define KVT 4104
#define SCALE 0.08838834764831843f
#define NCHUNK 16
#define CHUNK 256
#define PARTSZ 1040  // 8 m + 8 l + 8*128 acc
#define QKV_N 786432
#define ATTN_N 262144

typedef float f32x4_t __attribute__((ext_vector_type(4)));

__device__ __forceinline__ float4 nt_load4(const float* p) {
  f32x4_t v = __builtin_nontemporal_load(reinterpret_cast<const f32x4_t*>(p));
  return make_float4(v.x, v.y, v.z, v.w);
}

// wave-local LDS ordering: no barrier, just drain DS ops of this wave
#define WAVE_LDS_FENCE() asm volatile("s_waitcnt lgkmcnt(0)" ::: "memory")

// ---------------- GEMM: C[M][F] = X[M][K] * W[F][K]^T (fp32) ----------------
// SPLITK>1: block z writes its partial to C + z*128*Fdim (separate buffers).
template <int BM, int BN, int SPLITK>
__global__ __launch_bounds__(256) void gemm_xwt(const float* __restrict__ X,
                                                const float* __restrict__ W,
                                                float* __restrict__ C,
                                                int K, int Fdim) {
  constexpr int BK = 32;
  constexpr int RM = BM / 16;
  constexpr int RN = BN / 16;
  __shared__ float xs[BK][BM + 4];
  __shared__ float wss[BK][BN + 4];
  const int t = threadIdx.x;
  const int tm = t >> 4, tn = t & 15;
  const int m0 = blockIdx.y * BM, f0 = blockIdx.x * BN;
  const int kbeg = (SPLITK > 1) ? blockIdx.z * (K / SPLITK) : 0;
  const int kend = (SPLITK > 1) ? kbeg + K / SPLITK : K;
  if (SPLITK > 1) C += (size_t)blockIdx.z * 128 * Fdim;
  float acc[RM][RN];
#pragma unroll
  for (int i = 0; i < RM; ++i)
#pragma unroll
    for (int j = 0; j < RN; ++j) acc[i][j] = 0.f;

  for (int kk = kbeg; kk < kend; kk += BK) {
#pragma unroll
    for (int i = 0; i < (BM * BK) / 1024; ++i) {
      int j = t + i * 256;
      int r = j >> 3;
      int c = (j & 7) << 2;
      float4 v = *reinterpret_cast<const float4*>(&X[(size_t)(m0 + r) * K + kk + c]);
      xs[c + 0][r] = v.x; xs[c + 1][r] = v.y; xs[c + 2][r] = v.z; xs[c + 3][r] = v.w;
    }
#pragma unroll
    for (int i = 0; i < (BN * BK) / 1024; ++i) {
      int j = t + i * 256;
      int r = j >> 3;
      int c = (j & 7) << 2;
      float4 v = *reinterpret_cast<const float4*>(&W[(size_t)(f0 + r) * K + kk + c]);
      wss[c + 0][r] = v.x; wss[c + 1][r] = v.y; wss[c + 2][r] = v.z; wss[c + 3][r] = v.w;
    }
    __syncthreads();
#pragma unroll
    for (int k = 0; k < BK; ++k) {
      float xv[RM], wv[RN];
      if constexpr (RM == 4) {
        *reinterpret_cast<float4*>(xv) = *reinterpret_cast<const float4*>(&xs[k][tm * 4]);
      } else {
        *reinterpret_cast<float2*>(xv) = *reinterpret_cast<const float2*>(&xs[k][tm * 2]);
      }
      if constexpr (RN == 4) {
        *reinterpret_cast<float4*>(wv) = *reinterpret_cast<const float4*>(&wss[k][tn * 4]);
      } else {
        *reinterpret_cast<float2*>(wv) = *reinterpret_cast<const float2*>(&wss[k][tn * 2]);
      }
#pragma unroll
      for (int i = 0; i < RM; ++i)
#pragma unroll
        for (int j = 0; j < RN; ++j) acc[i][j] += xv[i] * wv[j];
    }
    __syncthreads();
  }
#pragma unroll
  for (int i = 0; i < RM; ++i) {
    float* cp = &C[(size_t)(m0 + tm * RM + i) * Fdim + f0 + tn * RN];
    if constexpr (RN == 4) {
      *reinterpret_cast<float4*>(cp) = make_float4(acc[i][0], acc[i][1], acc[i][2], acc[i][3]);
    } else {
      *reinterpret_cast<float2*>(cp) = make_float2(acc[i][0], acc[i][1]);
    }
  }
}

// o = sum of 4 partial buffers (stride n4*4 floats each), n4 float4s
__global__ __launch_bounds__(256) void add4(const float* __restrict__ a,
                                            float* __restrict__ o, int n) {
  int i = blockIdx.x * 256 + threadIdx.x;
  const float4* a4 = reinterpret_cast<const float4*>(a);
  int n4 = n >> 2;
  float4 v0 = a4[i], v1 = a4[i + n4], v2 = a4[i + 2 * n4], v3 = a4[i + 3 * n4];
  reinterpret_cast<float4*>(o)[i] =
      make_float4(v0.x + v1.x + v2.x + v3.x, v0.y + v1.y + v2.y + v3.y,
                  v0.z + v1.z + v2.z + v3.z, v0.w + v1.w + v2.w + v3.w);
}

// ------- Fused KV-cache copy + flash-attention partials over past chunks -------
// grid: (NCHUNK=16, H, B), 256 threads = 4 waves; wave w owns 64 rows (8 iters x 8).
// Zero barriers in main loop; in-register online softmax (R9); NT loads (read-once);
// copy-through stores issued AFTER PV (store-late) so load waits precede stores.
__global__ __launch_bounds__(256) void attn_partial(
    const float* __restrict__ past_k, const float* __restrict__ past_v,
    const float* __restrict__ qkv, int nbuf,
    float* __restrict__ out_k, float* __restrict__ out_v,
    float* __restrict__ part) {
  const int t = threadIdx.x;
  const int c = blockIdx.x, h = blockIdx.y, b = blockIdx.z;
  const int bh = b * H_ + h;
  const int l = t & 63, w = t >> 6;
  const int g = l & 31, half = l >> 5;

  __shared__ float red[4096];        // 16KB end-merge buffer [w][qi][128]
  __shared__ float pw_s[4][72];      // per-wave: p[8 rows][8 qi] | f[8] @64
  __shared__ float mw_lds[32], lw_lds[32];
  float* p_w = pw_s[w];
  float* f_w = pw_s[w] + 64;

  // Q resident in registers, pre-scaled (fixed f4-column g, all 8 q-rows)
  float4 qreg[NQ];
#pragma unroll
  for (int qi = 0; qi < NQ; ++qi) {
    const size_t qoff = (size_t)(b * NQ + qi) * F3 + h * D_ + g * 4;
    float4 q0 = *reinterpret_cast<const float4*>(&qkv[qoff]);
    for (int p = 1; p < nbuf; ++p) {
      float4 q1 = *reinterpret_cast<const float4*>(&qkv[(size_t)p * QKV_N + qoff]);
      q0.x += q1.x; q0.y += q1.y; q0.z += q1.z; q0.w += q1.w;
    }
    q0.x *= SCALE; q0.y *= SCALE; q0.z *= SCALE; q0.w *= SCALE;
    qreg[qi] = q0;
  }

  const int wbase = w * 64;
  const float* gk = past_k + ((size_t)bh * KVP + (size_t)c * CHUNK) * D_;
  const float* gv = past_v + ((size_t)bh * KVP + (size_t)c * CHUNK) * D_;
  float* ok = out_k + ((size_t)bh * KVT + (size_t)c * CHUNK) * D_;
  float* ov = out_v + ((size_t)bh * KVT + (size_t)c * CHUNK) * D_;

  float4 acc[NQ];
#pragma unroll
  for (int qi = 0; qi < NQ; ++qi) acc[qi] = make_float4(0.f, 0.f, 0.f, 0.f);
  float m_run = -1e30f, l_run = 0.f;  // per-lane state for qi = qsel

  const int b0 = g & 1, b1 = (g >> 1) & 1, b2 = (g >> 2) & 1;
  const int qsel = 4 * b0 + 2 * b1 + b2;  // qi this lane's butterfly output maps to
  const int cp = g >> 3;                  // butterfly copy index -> row half+2*cp

  for (int it = 0; it < 8; ++it) {
    // ---- NT-load 4 K/V rows (parity-interleaved), reg-direct scores ----
    float4 kf[4], vf[4];
#pragma unroll
    for (int j = 0; j < 4; ++j) {
      const size_t ga = (size_t)(wbase + it * 8 + half + 2 * j) * D_ + g * 4;
      kf[j] = nt_load4(&gk[ga]);
      vf[j] = nt_load4(&gv[ga]);
    }
    float s4[4];
#pragma unroll
    for (int j = 0; j < 4; ++j) {
      float sp[NQ];
#pragma unroll
      for (int qi = 0; qi < NQ; ++qi)
        sp[qi] = kf[j].x * qreg[qi].x + kf[j].y * qreg[qi].y +
                 kf[j].z * qreg[qi].z + kf[j].w * qreg[qi].w;
      // butterfly: 8 vals -> full dot on every lane of the 32-lane half (qi=qsel)
      float v1[4];
#pragma unroll
      for (int jj = 0; jj < 4; ++jj) {
        float x = b0 ? sp[jj] : sp[jj + 4];
        v1[jj] = (b0 ? sp[jj + 4] : sp[jj]) + __shfl_xor(x, 1);
      }
      float v2[2];
#pragma unroll
      for (int jj = 0; jj < 2; ++jj) {
        float x = b1 ? v1[jj] : v1[jj + 2];
        v2[jj] = (b1 ? v1[jj + 2] : v1[jj]) + __shfl_xor(x, 2);
      }
      float v3;
      {
        float x = b2 ? v2[0] : v2[1];
        v3 = (b2 ? v2[1] : v2[0]) + __shfl_xor(x, 4);
      }
      v3 += __shfl_xor(v3, 8);
      v3 += __shfl_xor(v3, 16);
      s4[j] = v3;
    }

    // ---- in-register online softmax for qi = qsel over this iter's 8 rows ----
    {
      float mt = fmaxf(fmaxf(s4[0], s4[1]), fmaxf(s4[2], s4[3]));
      mt = fmaxf(mt, __shfl_xor(mt, 32));   // other parity's rows
      float mn = fmaxf(m_run, mt);
      float f = __expf(m_run - mn);
      s4[0] = __expf(s4[0] - mn);
      s4[1] = __expf(s4[1] - mn);
      s4[2] = __expf(s4[2] - mn);
      s4[3] = __expf(s4[3] - mn);
      float ps = (s4[0] + s4[1]) + (s4[2] + s4[3]);
      ps += __shfl_xor(ps, 32);
      l_run = l_run * f + ps;
      m_run = mn;
      p_w[(half + 2 * cp) * 8 + qsel] = s4[cp];
      if (l < 8) f_w[qsel] = f;
    }
    WAVE_LDS_FENCE();  // p/f visible wave-wide

    // ---- PV on register V rows ----
    {
      float4 f0 = *reinterpret_cast<const float4*>(&f_w[0]);
      float4 f1 = *reinterpret_cast<const float4*>(&f_w[4]);
      acc[0].x *= f0.x; acc[0].y *= f0.x; acc[0].z *= f0.x; acc[0].w *= f0.x;
      acc[1].x *= f0.y; acc[1].y *= f0.y; acc[1].z *= f0.y; acc[1].w *= f0.y;
      acc[2].x *= f0.z; acc[2].y *= f0.z; acc[2].z *= f0.z; acc[2].w *= f0.z;
      acc[3].x *= f0.w; acc[3].y *= f0.w; acc[3].z *= f0.w; acc[3].w *= f0.w;
      acc[4].x *= f1.x; acc[4].y *= f1.x; acc[4].z *= f1.x; acc[4].w *= f1.x;
      acc[5].x *= f1.y; acc[5].y *= f1.y; acc[5].z *= f1.y; acc[5].w *= f1.y;
      acc[6].x *= f1.z; acc[6].y *= f1.z; acc[6].z *= f1.z; acc[6].w *= f1.z;
      acc[7].x *= f1.w; acc[7].y *= f1.w; acc[7].z *= f1.w; acc[7].w *= f1.w;
#pragma unroll
      for (int j = 0; j < 4; ++j) {
        const int r = half + 2 * j;
        float4 pa = *reinterpret_cast<const float4*>(&p_w[r * 8]);      // broadcast
        float4 pc4 = *reinterpret_cast<const float4*>(&p_w[r * 8 + 4]); // broadcast
        acc[0].x += pa.x * vf[j].x; acc[0].y += pa.x * vf[j].y; acc[0].z += pa.x * vf[j].z; acc[0].w += pa.x * vf[j].w;
        acc[1].x += pa.y * vf[j].x; acc[1].y += pa.y * vf[j].y; acc[1].z += pa.y * vf[j].z; acc[1].w += pa.y * vf[j].w;
        acc[2].x += pa.z * vf[j].x; acc[2].y += pa.z * vf[j].y; acc[2].z += pa.z * vf[j].z; acc[2].w += pa.z * vf[j].w;
        acc[3].x += pa.w * vf[j].x; acc[3].y += pa.w * vf[j].y; acc[3].z += pa.w * vf[j].z; acc[3].w += pa.w * vf[j].w;
        acc[4].x += pc4.x * vf[j].x; acc[4].y += pc4.x * vf[j].y; acc[4].z += pc4.x * vf[j].z; acc[4].w += pc4.x * vf[j].w;
        acc[5].x += pc4.y * vf[j].x; acc[5].y += pc4.y * vf[j].y; acc[5].z += pc4.y * vf[j].z; acc[5].w += pc4.y * vf[j].w;
        acc[6].x += pc4.z * vf[j].x; acc[6].y += pc4.z * vf[j].y; acc[6].z += pc4.z * vf[j].z; acc[6].w += pc4.z * vf[j].w;
        acc[7].x += pc4.w * vf[j].x; acc[7].y += pc4.w * vf[j].y; acc[7].z += pc4.w * vf[j].z; acc[7].w += pc4.w * vf[j].w;
      }
    }

    // ---- store-late copy-through (fire-and-forget after all load waits) ----
#pragma unroll
    for (int j = 0; j < 4; ++j) {
      const size_t ga = (size_t)(wbase + it * 8 + half + 2 * j) * D_ + g * 4;
      *reinterpret_cast<float4*>(&ok[ga]) = kf[j];
      *reinterpret_cast<float4*>(&ov[ga]) = vf[j];
    }
  }

  // ---- merge the two parity halves (same column g) ----
#pragma unroll
  for (int qi = 0; qi < NQ; ++qi) {
    acc[qi].x += __shfl_xor(acc[qi].x, 32);
    acc[qi].y += __shfl_xor(acc[qi].y, 32);
    acc[qi].z += __shfl_xor(acc[qi].z, 32);
    acc[qi].w += __shfl_xor(acc[qi].w, 32);
  }

  // ---- publish wave partials, single block barrier, merge 4 waves ----
  if (l < 8) { mw_lds[w * 8 + qsel] = m_run; lw_lds[w * 8 + qsel] = l_run; }
  if (half == 0) {
#pragma unroll
    for (int qi = 0; qi < NQ; ++qi)
      *reinterpret_cast<float4*>(&red[w * 1024 + qi * 128 + g * 4]) = acc[qi];
  }
  __syncthreads();

  {
    const int col4 = t & 31, qi = (t >> 5) & 7;
    float M = mw_lds[qi];
    M = fmaxf(M, mw_lds[8 + qi]);
    M = fmaxf(M, mw_lds[16 + qi]);
    M = fmaxf(M, mw_lds[24 + qi]);
    float den = 0.f;
    float4 num = make_float4(0.f, 0.f, 0.f, 0.f);
#pragma unroll
    for (int ww = 0; ww < 4; ++ww) {
      float wt = __expf(mw_lds[ww * 8 + qi] - M);
      den += wt * lw_lds[ww * 8 + qi];
      float4 a = *reinterpret_cast<const float4*>(&red[ww * 1024 + qi * 128 + col4 * 4]);
      num.x += wt * a.x; num.y += wt * a.y; num.z += wt * a.z; num.w += wt * a.w;
    }
    float* pb = part + ((size_t)bh * NCHUNK + c) * PARTSZ;
    *reinterpret_cast<float4*>(&pb[16 + qi * 128 + col4 * 4]) = num;
    if (col4 == 0) { pb[qi] = M; pb[8 + qi] = den; }
  }
}

// ------- new-token chunk + combine partials -> attention output (pre-proj) -------
// grid: (H, B), 256 threads.
__global__ __launch_bounds__(256) void attn_combine(
    const float* __restrict__ qkv, int nbuf,
    const float* __restrict__ part, float* __restrict__ out_k,
    float* __restrict__ out_v, float* __restrict__ attn) {
  const int t = threadIdx.x;
  const int h = blockIdx.x, b = blockIdx.y;
  const int bh = b * H_ + h;
  __shared__ float q_lds[NQ * 132];
  __shared__ float kn_lds[NQ * 132];
  __shared__ float vn_lds[NQ * 132];
  __shared__ float p9[NQ * 12];
  __shared__ float m9_lds[NQ], s9_lds[NQ];
  {
    int n = t >> 5, g = t & 31;
    const size_t soff = (size_t)(b * NQ + n) * F3 + h * D_ + g * 4;
    float4 qv = *reinterpret_cast<const float4*>(&qkv[soff]);
    float4 kv = *reinterpret_cast<const float4*>(&qkv[soff + E_]);
    float4 vv = *reinterpret_cast<const float4*>(&qkv[soff + 2 * E_]);
    for (int p = 1; p < nbuf; ++p) {
      const float* qb = qkv + (size_t)p * QKV_N;
      float4 q1 = *reinterpret_cast<const float4*>(&qb[soff]);
      float4 k1 = *reinterpret_cast<const float4*>(&qb[soff + E_]);
      float4 v1 = *reinterpret_cast<const float4*>(&qb[soff + 2 * E_]);
      qv.x += q1.x; qv.y += q1.y; qv.z += q1.z; qv.w += q1.w;
      kv.x += k1.x; kv.y += k1.y; kv.z += k1.z; kv.w += k1.w;
      vv.x += v1.x; vv.y += v1.y; vv.z += v1.z; vv.w += v1.w;
    }
    *reinterpret_cast<float4*>(&q_lds[n * 132 + g * 4]) = qv;
    *reinterpret_cast<float4*>(&kn_lds[n * 132 + g * 4]) = kv;
    *reinterpret_cast<float4*>(&vn_lds[n * 132 + g * 4]) = vv;
    *reinterpret_cast<float4*>(&out_k[((size_t)bh * KVT + KVP + n) * D_ + g * 4]) = kv;
    *reinterpret_cast<float4*>(&out_v[((size_t)bh * KVT + KVP + n) * D_ + g * 4]) = vv;
  }
  __syncthreads();
  if (t < 64) {
    int nq = t >> 3, nk = t & 7;
    float s = 0.f;
#pragma unroll
    for (int g = 0; g < 32; ++g) {
      float4 qv = *reinterpret_cast<const float4*>(&q_lds[nq * 132 + g * 4]);
      float4 kv = *reinterpret_cast<const float4*>(&kn_lds[nk * 132 + g * 4]);
      s += qv.x * kv.x + qv.y * kv.y + qv.z * kv.z + qv.w * kv.w;
    }
    s *= SCALE;
    float mx = s;
#pragma unroll
    for (int o = 4; o > 0; o >>= 1) mx = fmaxf(mx, __shfl_xor(mx, o));
    float p = __expf(s - mx);
    float sm = p;
#pragma unroll
    for (int o = 4; o > 0; o >>= 1) sm += __shfl_xor(sm, o);
    p9[nk * 12 + nq] = p;
    if (nk == 0) { m9_lds[nq] = mx; s9_lds[nq] = sm; }
  }
  __syncthreads();
  const int qg = t >> 7, dcol = t & 127;
  const float* pb = part + (size_t)bh * NCHUNK * PARTSZ;
#pragma unroll
  for (int jq = 0; jq < 4; ++jq) {
    int qi = qg * 4 + jq;
    float M = m9_lds[qi];
#pragma unroll
    for (int c = 0; c < NCHUNK; ++c) M = fmaxf(M, pb[(size_t)c * PARTSZ + qi]);
    float num = 0.f, den = 0.f;
#pragma unroll
    for (int c = 0; c < NCHUNK; ++c) {
      const float* pc = pb + (size_t)c * PARTSZ;
      float wgt = __expf(pc[qi] - M);
      den += wgt * pc[8 + qi];
      num += wgt * pc[16 + (size_t)qi * D_ + dcol];
    }
    float acc9 = 0.f;
#pragma unroll
    for (int r = 0; r < NQ; ++r) acc9 += p9[r * 12 + qi] * vn_lds[r * 132 + dcol];
    float w9 = __expf(m9_lds[qi] - M);
    num += w9 * acc9;
    den += w9 * s9_lds[qi];
    attn[((size_t)(b * NQ + qi)) * E_ + h * D_ + dcol] = num / den;
  }
}

extern "C" void kernel_launch(void* const* d_in, const int* in_sizes, int n_in,
                              void* d_out, int out_size, void* d_ws, size_t ws_size,
                              hipStream_t stream) {
  const float* x      = (const float*)d_in[0];
  const float* past_k = (const float*)d_in[1];
  const float* past_v = (const float*)d_in[2];
  const float* W_qkv  = (const float*)d_in[3];
  const float* W_out  = (const float*)d_in[4];

  float* out   = (float*)d_out;
  float* out_k = out + (size_t)B_ * NQ * E_;
  float* out_v = out_k + (size_t)B_ * H_ * KVT * D_;

  const size_t PART_N = (size_t)B_ * H_ * NCHUNK * PARTSZ;  // 4259840
  const size_t need4  = (4 * (size_t)QKV_N + PART_N + 5 * (size_t)ATTN_N) * sizeof(float);

  float* ws = (float*)d_ws;
  const bool s4 = ws_size >= need4;
  const int nbuf = s4 ? 4 : 1;

  float* pq   = ws;                                   // nbuf * QKV_N
  float* part = pq + (size_t)nbuf * QKV_N;            // PART_N
  float* attn = part + PART_N;                        // ATTN_N
  float* po   = attn + ATTN_N;                        // nbuf * ATTN_N (split path)

  if (s4) {
    gemm_xwt<64, 64, 4><<<dim3(F3 / 64, 2, 4), 256, 0, stream>>>(x, W_qkv, pq, E_, F3);
  } else {
    gemm_xwt<64, 64, 1><<<dim3(F3 / 64, 2), 256, 0, stream>>>(x, W_qkv, pq, E_, F3);
  }
  attn_partial<<<dim3(NCHUNK, H_, B_), 256, 0, stream>>>(past_k, past_v, pq, nbuf,
                                                         out_k, out_v, part);
  attn_combine<<<dim3(H_, B_), 256, 0, stream>>>(pq, nbuf, part, out_k, out_v, attn);
  if (s4) {
    gemm_xwt<64, 64, 4><<<dim3(E_ / 64, 2, 4), 256, 0, stream>>>(attn, W_out, po, E_, E_);
    add4<<<dim3(ATTN_N / 1024), 256, 0, stream>>>(po, out, ATTN_N);
  } else {
    gemm_xwt<64, 64, 1><<<dim3(E_ / 64, 2), 256, 0, stream>>>(attn, W_out, out, E_, E_);
  }
}

// Round 11
// 510.777 us; speedup vs baseline: 1.4016x; 1.0427x over previous
//
#include <hip/hip_runtime.h>
#include <cstddef>
#include <cstdint>

#define B_ 16
#define H_ 16
#define NQ 8
#define D_ 128
#define E_ 2048
#define F3 6144
#define KVP 4096
#define KVT 4104
#define SCALE 0.08838834764831843f
#define NCHUNK 16
#define CHUNK 256
#define PARTSZ 1040  // 8 m + 8 l + 8*128 acc
#define QKV_N 786432
#define ATTN_N 262144

typedef float f32x4_t __attribute__((ext_vector_type(4)));

__device__ __forceinline__ float4 nt_load4(const float* p) {
  f32x4_t v = __builtin_nontemporal_load(reinterpret_cast<const f32x4_t*>(p));
  return make_float4(v.x, v.y, v.z, v.w);
}

// wave-local LDS ordering: no barrier, just drain DS ops of this wave
#define WAVE_LDS_FENCE() asm volatile("s_waitcnt lgkmcnt(0)" ::: "memory")

// ---------------- GEMM: C[M][F] = X[M][K] * W[F][K]^T (fp32) ----------------
// SPLITK>1: block z writes its partial to C + z*128*Fdim (separate buffers).
template <int BM, int BN, int SPLITK>
__global__ __launch_bounds__(256) void gemm_xwt(const float* __restrict__ X,
                                                const float* __restrict__ W,
                                                float* __restrict__ C,
                                                int K, int Fdim) {
  constexpr int BK = 32;
  constexpr int RM = BM / 16;
  constexpr int RN = BN / 16;
  __shared__ float xs[BK][BM + 4];
  __shared__ float wss[BK][BN + 4];
  const int t = threadIdx.x;
  const int tm = t >> 4, tn = t & 15;
  const int m0 = blockIdx.y * BM, f0 = blockIdx.x * BN;
  const int kbeg = (SPLITK > 1) ? blockIdx.z * (K / SPLITK) : 0;
  const int kend = (SPLITK > 1) ? kbeg + K / SPLITK : K;
  if (SPLITK > 1) C += (size_t)blockIdx.z * 128 * Fdim;
  float acc[RM][RN];
#pragma unroll
  for (int i = 0; i < RM; ++i)
#pragma unroll
    for (int j = 0; j < RN; ++j) acc[i][j] = 0.f;

  for (int kk = kbeg; kk < kend; kk += BK) {
#pragma unroll
    for (int i = 0; i < (BM * BK) / 1024; ++i) {
      int j = t + i * 256;
      int r = j >> 3;
      int c = (j & 7) << 2;
      float4 v = *reinterpret_cast<const float4*>(&X[(size_t)(m0 + r) * K + kk + c]);
      xs[c + 0][r] = v.x; xs[c + 1][r] = v.y; xs[c + 2][r] = v.z; xs[c + 3][r] = v.w;
    }
#pragma unroll
    for (int i = 0; i < (BN * BK) / 1024; ++i) {
      int j = t + i * 256;
      int r = j >> 3;
      int c = (j & 7) << 2;
      float4 v = *reinterpret_cast<const float4*>(&W[(size_t)(f0 + r) * K + kk + c]);
      wss[c + 0][r] = v.x; wss[c + 1][r] = v.y; wss[c + 2][r] = v.z; wss[c + 3][r] = v.w;
    }
    __syncthreads();
#pragma unroll
    for (int k = 0; k < BK; ++k) {
      float xv[RM], wv[RN];
      if constexpr (RM == 4) {
        *reinterpret_cast<float4*>(xv) = *reinterpret_cast<const float4*>(&xs[k][tm * 4]);
      } else {
        *reinterpret_cast<float2*>(xv) = *reinterpret_cast<const float2*>(&xs[k][tm * 2]);
      }
      if constexpr (RN == 4) {
        *reinterpret_cast<float4*>(wv) = *reinterpret_cast<const float4*>(&wss[k][tn * 4]);
      } else {
        *reinterpret_cast<float2*>(wv) = *reinterpret_cast<const float2*>(&wss[k][tn * 2]);
      }
#pragma unroll
      for (int i = 0; i < RM; ++i)
#pragma unroll
        for (int j = 0; j < RN; ++j) acc[i][j] += xv[i] * wv[j];
    }
    __syncthreads();
  }
#pragma unroll
  for (int i = 0; i < RM; ++i) {
    float* cp = &C[(size_t)(m0 + tm * RM + i) * Fdim + f0 + tn * RN];
    if constexpr (RN == 4) {
      *reinterpret_cast<float4*>(cp) = make_float4(acc[i][0], acc[i][1], acc[i][2], acc[i][3]);
    } else {
      *reinterpret_cast<float2*>(cp) = make_float2(acc[i][0], acc[i][1]);
    }
  }
}

// o = sum of 4 partial buffers (stride n4*4 floats each), n4 float4s
__global__ __launch_bounds__(256) void add4(const float* __restrict__ a,
                                            float* __restrict__ o, int n) {
  int i = blockIdx.x * 256 + threadIdx.x;
  const float4* a4 = reinterpret_cast<const float4*>(a);
  int n4 = n >> 2;
  float4 v0 = a4[i], v1 = a4[i + n4], v2 = a4[i + 2 * n4], v3 = a4[i + 3 * n4];
  reinterpret_cast<float4*>(o)[i] =
      make_float4(v0.x + v1.x + v2.x + v3.x, v0.y + v1.y + v2.y + v3.y,
                  v0.z + v1.z + v2.z + v3.z, v0.w + v1.w + v2.w + v3.w);
}

// ------- Fused KV-cache copy + flash-attention partials over past chunks -------
// grid: (NCHUNK=16, H, B), 256 threads = 4 waves; wave w owns 64 rows (8 iters x 8).
// Zero barriers in main loop; in-register online softmax; NT loads; store-late.
// Software pipeline: K is prefetched one iter ahead (K-only, +16 VGPR); V is issued
// at iter top and consumed after scores+softmax (~600cy of cover). No load is
// consumed in the same instruction window it was issued.
__global__ __launch_bounds__(256) void attn_partial(
    const float* __restrict__ past_k, const float* __restrict__ past_v,
    const float* __restrict__ qkv, int nbuf,
    float* __restrict__ out_k, float* __restrict__ out_v,
    float* __restrict__ part) {
  const int t = threadIdx.x;
  const int c = blockIdx.x, h = blockIdx.y, b = blockIdx.z;
  const int bh = b * H_ + h;
  const int l = t & 63, w = t >> 6;
  const int g = l & 31, half = l >> 5;

  __shared__ float red[4096];        // 16KB end-merge buffer [w][qi][128]
  __shared__ float pw_s[4][72];      // per-wave: p[8 rows][8 qi] | f[8] @64
  __shared__ float mw_lds[32], lw_lds[32];
  float* p_w = pw_s[w];
  float* f_w = pw_s[w] + 64;

  // Q resident in registers, pre-scaled (fixed f4-column g, all 8 q-rows)
  float4 qreg[NQ];
#pragma unroll
  for (int qi = 0; qi < NQ; ++qi) {
    const size_t qoff = (size_t)(b * NQ + qi) * F3 + h * D_ + g * 4;
    float4 q0 = *reinterpret_cast<const float4*>(&qkv[qoff]);
    for (int p = 1; p < nbuf; ++p) {
      float4 q1 = *reinterpret_cast<const float4*>(&qkv[(size_t)p * QKV_N + qoff]);
      q0.x += q1.x; q0.y += q1.y; q0.z += q1.z; q0.w += q1.w;
    }
    q0.x *= SCALE; q0.y *= SCALE; q0.z *= SCALE; q0.w *= SCALE;
    qreg[qi] = q0;
  }

  const int wbase = w * 64;
  const float* gk = past_k + ((size_t)bh * KVP + (size_t)c * CHUNK) * D_;
  const float* gv = past_v + ((size_t)bh * KVP + (size_t)c * CHUNK) * D_;
  float* ok = out_k + ((size_t)bh * KVT + (size_t)c * CHUNK) * D_;
  float* ov = out_v + ((size_t)bh * KVT + (size_t)c * CHUNK) * D_;

  float4 acc[NQ];
#pragma unroll
  for (int qi = 0; qi < NQ; ++qi) acc[qi] = make_float4(0.f, 0.f, 0.f, 0.f);
  float m_run = -1e30f, l_run = 0.f;  // per-lane state for qi = qsel

  const int b0 = g & 1, b1 = (g >> 1) & 1, b2 = (g >> 2) & 1;
  const int qsel = 4 * b0 + 2 * b1 + b2;  // qi this lane's butterfly output maps to
  const int cp = g >> 3;                  // butterfly copy index -> row half+2*cp

  // body for one iter: kf holds K_it (already loaded); kn receives K_{it+1} if pf
  auto body = [&](float4 (&kf)[4], float4 (&kn)[4], int it, bool pf) {
    // ---- issue V loads for this iter (consumed after scores+softmax) ----
    float4 vf[4];
#pragma unroll
    for (int j = 0; j < 4; ++j) {
      const size_t ga = (size_t)(wbase + it * 8 + half + 2 * j) * D_ + g * 4;
      vf[j] = nt_load4(&gv[ga]);
    }
    // ---- scores from resident K (no memory wait) ----
    float s4[4];
#pragma unroll
    for (int j = 0; j < 4; ++j) {
      float sp[NQ];
#pragma unroll
      for (int qi = 0; qi < NQ; ++qi)
        sp[qi] = kf[j].x * qreg[qi].x + kf[j].y * qreg[qi].y +
                 kf[j].z * qreg[qi].z + kf[j].w * qreg[qi].w;
      // butterfly: 8 vals -> full dot on every lane of the 32-lane half (qi=qsel)
      float v1[4];
#pragma unroll
      for (int jj = 0; jj < 4; ++jj) {
        float x = b0 ? sp[jj] : sp[jj + 4];
        v1[jj] = (b0 ? sp[jj + 4] : sp[jj]) + __shfl_xor(x, 1);
      }
      float v2[2];
#pragma unroll
      for (int jj = 0; jj < 2; ++jj) {
        float x = b1 ? v1[jj] : v1[jj + 2];
        v2[jj] = (b1 ? v1[jj + 2] : v1[jj]) + __shfl_xor(x, 2);
      }
      float v3;
      {
        float x = b2 ? v2[0] : v2[1];
        v3 = (b2 ? v2[1] : v2[0]) + __shfl_xor(x, 4);
      }
      v3 += __shfl_xor(v3, 8);
      v3 += __shfl_xor(v3, 16);
      s4[j] = v3;
    }
    // ---- in-register online softmax for qi = qsel over this iter's 8 rows ----
    {
      float mt = fmaxf(fmaxf(s4[0], s4[1]), fmaxf(s4[2], s4[3]));
      mt = fmaxf(mt, __shfl_xor(mt, 32));   // other parity's rows
      float mn = fmaxf(m_run, mt);
      float f = __expf(m_run - mn);
      s4[0] = __expf(s4[0] - mn);
      s4[1] = __expf(s4[1] - mn);
      s4[2] = __expf(s4[2] - mn);
      s4[3] = __expf(s4[3] - mn);
      float ps = (s4[0] + s4[1]) + (s4[2] + s4[3]);
      ps += __shfl_xor(ps, 32);
      l_run = l_run * f + ps;
      m_run = mn;
      p_w[(half + 2 * cp) * 8 + qsel] = s4[cp];
      if (l < 8) f_w[qsel] = f;
    }
    WAVE_LDS_FENCE();  // p/f visible wave-wide

    // ---- prefetch next iter's K (hidden under PV) ----
    if (pf) {
#pragma unroll
      for (int j = 0; j < 4; ++j) {
        const size_t ga = (size_t)(wbase + (it + 1) * 8 + half + 2 * j) * D_ + g * 4;
        kn[j] = nt_load4(&gk[ga]);
      }
    }

    // ---- PV on register V rows (V issued ~600cy ago) ----
    {
      float4 f0 = *reinterpret_cast<const float4*>(&f_w[0]);
      float4 f1 = *reinterpret_cast<const float4*>(&f_w[4]);
      acc[0].x *= f0.x; acc[0].y *= f0.x; acc[0].z *= f0.x; acc[0].w *= f0.x;
      acc[1].x *= f0.y; acc[1].y *= f0.y; acc[1].z *= f0.y; acc[1].w *= f0.y;
      acc[2].x *= f0.z; acc[2].y *= f0.z; acc[2].z *= f0.z; acc[2].w *= f0.z;
      acc[3].x *= f0.w; acc[3].y *= f0.w; acc[3].z *= f0.w; acc[3].w *= f0.w;
      acc[4].x *= f1.x; acc[4].y *= f1.x; acc[4].z *= f1.x; acc[4].w *= f1.x;
      acc[5].x *= f1.y; acc[5].y *= f1.y; acc[5].z *= f1.y; acc[5].w *= f1.y;
      acc[6].x *= f1.z; acc[6].y *= f1.z; acc[6].z *= f1.z; acc[6].w *= f1.z;
      acc[7].x *= f1.w; acc[7].y *= f1.w; acc[7].z *= f1.w; acc[7].w *= f1.w;
#pragma unroll
      for (int j = 0; j < 4; ++j) {
        const int r = half + 2 * j;
        float4 pa = *reinterpret_cast<const float4*>(&p_w[r * 8]);      // broadcast
        float4 pc4 = *reinterpret_cast<const float4*>(&p_w[r * 8 + 4]); // broadcast
        acc[0].x += pa.x * vf[j].x; acc[0].y += pa.x * vf[j].y; acc[0].z += pa.x * vf[j].z; acc[0].w += pa.x * vf[j].w;
        acc[1].x += pa.y * vf[j].x; acc[1].y += pa.y * vf[j].y; acc[1].z += pa.y * vf[j].z; acc[1].w += pa.y * vf[j].w;
        acc[2].x += pa.z * vf[j].x; acc[2].y += pa.z * vf[j].y; acc[2].z += pa.z * vf[j].z; acc[2].w += pa.z * vf[j].w;
        acc[3].x += pa.w * vf[j].x; acc[3].y += pa.w * vf[j].y; acc[3].z += pa.w * vf[j].z; acc[3].w += pa.w * vf[j].w;
        acc[4].x += pc4.x * vf[j].x; acc[4].y += pc4.x * vf[j].y; acc[4].z += pc4.x * vf[j].z; acc[4].w += pc4.x * vf[j].w;
        acc[5].x += pc4.y * vf[j].x; acc[5].y += pc4.y * vf[j].y; acc[5].z += pc4.y * vf[j].z; acc[5].w += pc4.y * vf[j].w;
        acc[6].x += pc4.z * vf[j].x; acc[6].y += pc4.z * vf[j].y; acc[6].z += pc4.z * vf[j].z; acc[6].w += pc4.z * vf[j].w;
        acc[7].x += pc4.w * vf[j].x; acc[7].y += pc4.w * vf[j].y; acc[7].z += pc4.w * vf[j].z; acc[7].w += pc4.w * vf[j].w;
      }
    }

    // ---- store-late copy-through ----
#pragma unroll
    for (int j = 0; j < 4; ++j) {
      const size_t ga = (size_t)(wbase + it * 8 + half + 2 * j) * D_ + g * 4;
      *reinterpret_cast<float4*>(&ok[ga]) = kf[j];
      *reinterpret_cast<float4*>(&ov[ga]) = vf[j];
    }
  };

  float4 kA[4], kB[4];
#pragma unroll
  for (int j = 0; j < 4; ++j)
    kA[j] = nt_load4(&gk[(size_t)(wbase + half + 2 * j) * D_ + g * 4]);

  for (int it = 0; it < 8; it += 2) {
    body(kA, kB, it, true);
    body(kB, kA, it + 1, it + 2 < 8);
  }

  // ---- merge the two parity halves (same column g) ----
#pragma unroll
  for (int qi = 0; qi < NQ; ++qi) {
    acc[qi].x += __shfl_xor(acc[qi].x, 32);
    acc[qi].y += __shfl_xor(acc[qi].y, 32);
    acc[qi].z += __shfl_xor(acc[qi].z, 32);
    acc[qi].w += __shfl_xor(acc[qi].w, 32);
  }

  // ---- publish wave partials, single block barrier, merge 4 waves ----
  if (l < 8) { mw_lds[w * 8 + qsel] = m_run; lw_lds[w * 8 + qsel] = l_run; }
  if (half == 0) {
#pragma unroll
    for (int qi = 0; qi < NQ; ++qi)
      *reinterpret_cast<float4*>(&red[w * 1024 + qi * 128 + g * 4]) = acc[qi];
  }
  __syncthreads();

  {
    const int col4 = t & 31, qi = (t >> 5) & 7;
    float M = mw_lds[qi];
    M = fmaxf(M, mw_lds[8 + qi]);
    M = fmaxf(M, mw_lds[16 + qi]);
    M = fmaxf(M, mw_lds[24 + qi]);
    float den = 0.f;
    float4 num = make_float4(0.f, 0.f, 0.f, 0.f);
#pragma unroll
    for (int ww = 0; ww < 4; ++ww) {
      float wt = __expf(mw_lds[ww * 8 + qi] - M);
      den += wt * lw_lds[ww * 8 + qi];
      float4 a = *reinterpret_cast<const float4*>(&red[ww * 1024 + qi * 128 + col4 * 4]);
      num.x += wt * a.x; num.y += wt * a.y; num.z += wt * a.z; num.w += wt * a.w;
    }
    float* pb = part + ((size_t)bh * NCHUNK + c) * PARTSZ;
    *reinterpret_cast<float4*>(&pb[16 + qi * 128 + col4 * 4]) = num;
    if (col4 == 0) { pb[qi] = M; pb[8 + qi] = den; }
  }
}

// ------- new-token chunk + combine partials -> attention output (pre-proj) -------
// grid: (H, B), 256 threads.
__global__ __launch_bounds__(256) void attn_combine(
    const float* __restrict__ qkv, int nbuf,
    const float* __restrict__ part, float* __restrict__ out_k,
    float* __restrict__ out_v, float* __restrict__ attn) {
  const int t = threadIdx.x;
  const int h = blockIdx.x, b = blockIdx.y;
  const int bh = b * H_ + h;
  __shared__ float q_lds[NQ * 132];
  __shared__ float kn_lds[NQ * 132];
  __shared__ float vn_lds[NQ * 132];
  __shared__ float p9[NQ * 12];
  __shared__ float m9_lds[NQ], s9_lds[NQ];
  {
    int n = t >> 5, g = t & 31;
    const size_t soff = (size_t)(b * NQ + n) * F3 + h * D_ + g * 4;
    float4 qv = *reinterpret_cast<const float4*>(&qkv[soff]);
    float4 kv = *reinterpret_cast<const float4*>(&qkv[soff + E_]);
    float4 vv = *reinterpret_cast<const float4*>(&qkv[soff + 2 * E_]);
    for (int p = 1; p < nbuf; ++p) {
      const float* qb = qkv + (size_t)p * QKV_N;
      float4 q1 = *reinterpret_cast<const float4*>(&qb[soff]);
      float4 k1 = *reinterpret_cast<const float4*>(&qb[soff + E_]);
      float4 v1 = *reinterpret_cast<const float4*>(&qb[soff + 2 * E_]);
      qv.x += q1.x; qv.y += q1.y; qv.z += q1.z; qv.w += q1.w;
      kv.x += k1.x; kv.y += k1.y; kv.z += k1.z; kv.w += k1.w;
      vv.x += v1.x; vv.y += v1.y; vv.z += v1.z; vv.w += v1.w;
    }
    *reinterpret_cast<float4*>(&q_lds[n * 132 + g * 4]) = qv;
    *reinterpret_cast<float4*>(&kn_lds[n * 132 + g * 4]) = kv;
    *reinterpret_cast<float4*>(&vn_lds[n * 132 + g * 4]) = vv;
    *reinterpret_cast<float4*>(&out_k[((size_t)bh * KVT + KVP + n) * D_ + g * 4]) = kv;
    *reinterpret_cast<float4*>(&out_v[((size_t)bh * KVT + KVP + n) * D_ + g * 4]) = vv;
  }
  __syncthreads();
  if (t < 64) {
    int nq = t >> 3, nk = t & 7;
    float s = 0.f;
#pragma unroll
    for (int g = 0; g < 32; ++g) {
      float4 qv = *reinterpret_cast<const float4*>(&q_lds[nq * 132 + g * 4]);
      float4 kv = *reinterpret_cast<const float4*>(&kn_lds[nk * 132 + g * 4]);
      s += qv.x * kv.x + qv.y * kv.y + qv.z * kv.z + qv.w * kv.w;
    }
    s *= SCALE;
    float mx = s;
#pragma unroll
    for (int o = 4; o > 0; o >>= 1) mx = fmaxf(mx, __shfl_xor(mx, o));
    float p = __expf(s - mx);
    float sm = p;
#pragma unroll
    for (int o = 4; o > 0; o >>= 1) sm += __shfl_xor(sm, o);
    p9[nk * 12 + nq] = p;
    if (nk == 0) { m9_lds[nq] = mx; s9_lds[nq] = sm; }
  }
  __syncthreads();
  const int qg = t >> 7, dcol = t & 127;
  const float* pb = part + (size_t)bh * NCHUNK * PARTSZ;
#pragma unroll
  for (int jq = 0; jq < 4; ++jq) {
    int qi = qg * 4 + jq;
    float M = m9_lds[qi];
#pragma unroll
    for (int c = 0; c < NCHUNK; ++c) M = fmaxf(M, pb[(size_t)c * PARTSZ + qi]);
    float num = 0.f, den = 0.f;
#pragma unroll
    for (int c = 0; c < NCHUNK; ++c) {
      const float* pc = pb + (size_t)c * PARTSZ;
      float wgt = __expf(pc[qi] - M);
      den += wgt * pc[8 + qi];
      num += wgt * pc[16 + (size_t)qi * D_ + dcol];
    }
    float acc9 = 0.f;
#pragma unroll
    for (int r = 0; r < NQ; ++r) acc9 += p9[r * 12 + qi] * vn_lds[r * 132 + dcol];
    float w9 = __expf(m9_lds[qi] - M);
    num += w9 * acc9;
    den += w9 * s9_lds[qi];
    attn[((size_t)(b * NQ + qi)) * E_ + h * D_ + dcol] = num / den;
  }
}

extern "C" void kernel_launch(void* const* d_in, const int* in_sizes, int n_in,
                              void* d_out, int out_size, void* d_ws, size_t ws_size,
                              hipStream_t stream) {
  const float* x      = (const float*)d_in[0];
  const float* past_k = (const float*)d_in[1];
  const float* past_v = (const float*)d_in[2];
  const float* W_qkv  = (const float*)d_in[3];
  const float* W_out  = (const float*)d_in[4];

  float* out   = (float*)d_out;
  float* out_k = out + (size_t)B_ * NQ * E_;
  float* out_v = out_k + (size_t)B_ * H_ * KVT * D_;

  const size_t PART_N = (size_t)B_ * H_ * NCHUNK * PARTSZ;  // 4259840
  const size_t need4  = (4 * (size_t)QKV_N + PART_N + 5 * (size_t)ATTN_N) * sizeof(float);

  float* ws = (float*)d_ws;
  const bool s4 = ws_size >= need4;
  const int nbuf = s4 ? 4 : 1;

  float* pq   = ws;                                   // nbuf * QKV_N
  float* part = pq + (size_t)nbuf * QKV_N;            // PART_N
  float* attn = part + PART_N;                        // ATTN_N
  float* po   = attn + ATTN_N;                        // nbuf * ATTN_N (split path)

  if (s4) {
    gemm_xwt<64, 64, 4><<<dim3(F3 / 64, 2, 4), 256, 0, stream>>>(x, W_qkv, pq, E_, F3);
  } else {
    gemm_xwt<64, 64, 1><<<dim3(F3 / 64, 2), 256, 0, stream>>>(x, W_qkv, pq, E_, F3);
  }
  attn_partial<<<dim3(NCHUNK, H_, B_), 256, 0, stream>>>(past_k, past_v, pq, nbuf,
                                                         out_k, out_v, part);
  attn_combine<<<dim3(H_, B_), 256, 0, stream>>>(pq, nbuf, part, out_k, out_v, attn);
  if (s4) {
    gemm_xwt<64, 64, 4><<<dim3(E_ / 64, 2, 4), 256, 0, stream>>>(attn, W_out, po, E_, E_);
    add4<<<dim3(ATTN_N / 1024), 256, 0, stream>>>(po, out, ATTN_N);
  } else {
    gemm_xwt<64, 64, 1><<<dim3(E_ / 64, 2), 256, 0, stream>>>(attn, W_out, out, E_, E_);
  }
}